// Round 2
// baseline (582.811 us; speedup 1.0000x reference)
//
#include <hip/hip_runtime.h>
#include <hip/hip_bf16.h>

#define NPTS 1048576
#define NCLU 16384
#define DF   64
#define H1   128
#define H2   64
#define BP   64        // points per block
#define K1P  104       // LDS stride (elems) for K=96 (67 valid + zero pad), +8 pad
#define K2P  136       // LDS stride for K=128, +8 pad

typedef __bf16 bf16x8 __attribute__((ext_vector_type(8)));
typedef float  f32x4  __attribute__((ext_vector_type(4)));
typedef unsigned short u16x4 __attribute__((ext_vector_type(4)));

__device__ __forceinline__ unsigned short f2b(float f) {
  unsigned v; __builtin_memcpy(&v, &f, 4);
  v += 0x7fffu + ((v >> 16) & 1u);          // round-to-nearest-even
  return (unsigned short)(v >> 16);
}

__global__ __launch_bounds__(256, 2)
void fused_gather_mlp(const float* __restrict__ feat,
                      const int* __restrict__ labels,
                      const float* __restrict__ centers,
                      const float* __restrict__ points,
                      const float* __restrict__ W1,
                      const float* __restrict__ b1,
                      const float* __restrict__ W2,
                      const float* __restrict__ b2,
                      float* __restrict__ out)
{
  __shared__ __align__(16) unsigned short sX[BP][K1P];   // x tile bf16, K-padded to 96 w/ zeros
  __shared__ __align__(16) unsigned short sW1[H1][K1P];  // W1^T bf16: [n][k]
  __shared__ __align__(16) unsigned short sH[BP][K2P];   // hidden bf16
  __shared__ __align__(16) unsigned short sW2[H2][K2P];  // W2^T bf16: [n][k]
  __shared__ __align__(16) float sB1[H1];
  __shared__ __align__(16) float sB2[H2];
  __shared__ int sLab[BP];

  const int t  = threadIdx.x;
  const int p0 = blockIdx.x * BP;

  // ---------------- Phase A: labels, weights (fp32 -> bf16 transpose), biases, pads ----
  if (t < BP) sLab[t] = labels[p0 + t];
  if (t >= 64 && t < 96)  *(f32x4*)&sB1[(t - 64) * 4] = *(const f32x4*)&b1[(t - 64) * 4];
  if (t >= 96 && t < 112) *(f32x4*)&sB2[(t - 96) * 4] = *(const f32x4*)&b2[(t - 96) * 4];

  // W1 [67][128] fp32 row-major -> sW1[n][k] bf16; 8576 floats = 2144 float4 chunks
  for (int c = t; c < (67 * H1) / 4; c += 256) {
    f32x4 v = *(const f32x4*)&W1[c * 4];
    int k = c >> 5;            // 32 float4-chunks per 128-wide row
    int n = (c & 31) * 4;
    #pragma unroll
    for (int j = 0; j < 4; ++j) sW1[n + j][k] = f2b(v[j]);
  }
  // zero sW1 pad k=67..95
  for (int i = t; i < H1 * 32; i += 256) {
    int n = i >> 5, k = 67 + (i & 31);
    if (k < 96) sW1[n][k] = 0;
  }
  // W2 [128][64] fp32 row-major -> sW2[n][k] bf16; 8192 floats = 2048 chunks
  for (int c = t; c < (H1 * H2) / 4; c += 256) {
    f32x4 v = *(const f32x4*)&W2[c * 4];
    int k = c >> 4;            // 16 float4-chunks per 64-wide row
    int n = (c & 15) * 4;
    #pragma unroll
    for (int j = 0; j < 4; ++j) sW2[n + j][k] = f2b(v[j]);
  }
  // zero sX pad cols k=67..95
  for (int i = t; i < BP * 32; i += 256) {
    int r = i >> 5, k = 67 + (i & 31);
    if (k < 96) sX[r][k] = 0;
  }
  __syncthreads();

  // ---------------- Phase B: gather features (fp32->bf16) + coord diffs ----------------
  // 64 rows x 16 float4 chunks
  for (int task = t; task < BP * 16; task += 256) {
    int row = task >> 4, c = task & 15;
    int lab = sLab[row];
    f32x4 v = *(const f32x4*)&feat[lab * DF + c * 4];
    u16x4 h;
    #pragma unroll
    for (int j = 0; j < 4; ++j) h[j] = f2b(v[j]);
    *(u16x4*)&sX[row][c * 4] = h;           // 8B store, 8B-aligned (stride 208B)
  }
  if (t < BP) {
    int lab = sLab[t];
    int p = p0 + t;
    #pragma unroll
    for (int j = 0; j < 3; ++j) {
      float d = centers[lab * 3 + j] - points[p * 3 + j];
      sX[t][DF + j] = f2b(d);
    }
  }
  __syncthreads();

  // ---------------- GEMM1: [64,96] x [96,128] ----------------
  const int w = t >> 6, lane = t & 63;
  const int quad = lane >> 4, l16 = lane & 15;
  const int m0 = w * 16;    // wave-private 16-row M tile

  f32x4 acc[8];
  #pragma unroll
  for (int i = 0; i < 8; ++i) acc[i] = (f32x4){0.f, 0.f, 0.f, 0.f};

  #pragma unroll
  for (int ks = 0; ks < 3; ++ks) {
    int k0 = ks * 32 + quad * 8;
    bf16x8 a = *(const bf16x8*)&sX[m0 + l16][k0];
    #pragma unroll
    for (int nt = 0; nt < 8; ++nt) {
      bf16x8 b = *(const bf16x8*)&sW1[nt * 16 + l16][k0];
      acc[nt] = __builtin_amdgcn_mfma_f32_16x16x32_bf16(a, b, acc[nt], 0, 0, 0);
    }
  }
  // epilogue 1: bias + relu -> bf16 -> sH (wave-private rows; in-wave ordering, no barrier)
  #pragma unroll
  for (int nt = 0; nt < 8; ++nt) {
    int n = nt * 16 + l16;
    float bias = sB1[n];
    #pragma unroll
    for (int r = 0; r < 4; ++r) {
      float v = acc[nt][r] + bias;
      v = v > 0.f ? v : 0.f;
      sH[m0 + quad * 4 + r][n] = f2b(v);
    }
  }

  // ---------------- GEMM2: [64,128] x [128,64] ----------------
  f32x4 acc2[4];
  #pragma unroll
  for (int i = 0; i < 4; ++i) acc2[i] = (f32x4){0.f, 0.f, 0.f, 0.f};

  #pragma unroll
  for (int ks = 0; ks < 4; ++ks) {
    int k0 = ks * 32 + quad * 8;
    bf16x8 a = *(const bf16x8*)&sH[m0 + l16][k0];
    #pragma unroll
    for (int nt = 0; nt < 4; ++nt) {
      bf16x8 b = *(const bf16x8*)&sW2[nt * 16 + l16][k0];
      acc2[nt] = __builtin_amdgcn_mfma_f32_16x16x32_bf16(a, b, acc2[nt], 0, 0, 0);
    }
  }
  // epilogue 2: bias + relu -> fp32 global stores
  #pragma unroll
  for (int nt = 0; nt < 4; ++nt) {
    int n = nt * 16 + l16;
    float bias = sB2[n];
    #pragma unroll
    for (int r = 0; r < 4; ++r) {
      float v = acc2[nt][r] + bias;
      v = v > 0.f ? v : 0.f;
      out[(long)(p0 + m0 + quad * 4 + r) * H2 + n] = v;
    }
  }
}

extern "C" void kernel_launch(void* const* d_in, const int* in_sizes, int n_in,
                              void* d_out, int out_size, void* d_ws, size_t ws_size,
                              hipStream_t stream) {
  const float* feat   = (const float*)d_in[0];
  const int*   labels = (const int*)d_in[1];
  const float* cen    = (const float*)d_in[2];
  const float* pts    = (const float*)d_in[3];
  const float* W1     = (const float*)d_in[4];
  const float* b1     = (const float*)d_in[5];
  const float* W2     = (const float*)d_in[6];
  const float* b2     = (const float*)d_in[7];
  float*       outp   = (float*)d_out;

  fused_gather_mlp<<<dim3(NPTS / BP), dim3(256), 0, stream>>>(
      feat, labels, cen, pts, W1, b1, W2, b2, outp);
}

// Round 3
// 381.098 us; speedup vs baseline: 1.5293x; 1.5293x over previous
//
#include <hip/hip_runtime.h>
#include <hip/hip_bf16.h>

#define NPTS 1048576
#define NCLU 16384
#define DF   64
#define H1   128
#define H2   64
#define BP   64        // points per tile
#define NBLK 1024      // persistent blocks (2 per CU)
#define ITERS (NPTS / (BP * NBLK))   // 16 tiles per block
#define K1P  104       // LDS row stride (u16) for K=96 (67 valid + zero pad)
#define K2P  136       // LDS row stride (u16) for K=128

typedef __bf16 bf16x8 __attribute__((ext_vector_type(8)));
typedef float  f32x4  __attribute__((ext_vector_type(4)));
typedef unsigned short u16x4 __attribute__((ext_vector_type(4)));
typedef unsigned short u16x8 __attribute__((ext_vector_type(8)));

__device__ __forceinline__ unsigned short f2b(float f) {
  unsigned v; __builtin_memcpy(&v, &f, 4);
  v += 0x7fffu + ((v >> 16) & 1u);          // round-to-nearest-even
  return (unsigned short)(v >> 16);
}

// pre-kernel: feat fp32 [16384][64] -> bf16 u16 same layout in ws
__global__ __launch_bounds__(256, 4)
void cvt_feat(const float* __restrict__ f, unsigned short* __restrict__ o) {
  int i = (blockIdx.x * 256 + threadIdx.x) * 4;
  f32x4 v = *(const f32x4*)&f[i];
  u16x4 h;
  #pragma unroll
  for (int j = 0; j < 4; ++j) h[j] = f2b(v[j]);
  *(u16x4*)&o[i] = h;
}

__global__ __launch_bounds__(256, 2)
void fused_gather_mlp(const float* __restrict__ feat,
                      const int* __restrict__ labels,
                      const float* __restrict__ centers,
                      const float* __restrict__ points,
                      const float* __restrict__ W1,
                      const float* __restrict__ b1,
                      const float* __restrict__ W2,
                      const float* __restrict__ b2,
                      float* __restrict__ out,
                      const unsigned short* __restrict__ featbf,
                      int use_bf)
{
  __shared__ __align__(16) unsigned short sX[BP][K1P];   // x tile bf16 (wave-private rows)
  __shared__ __align__(16) unsigned short sW1[H1][K1P];  // W1^T bf16 [n][k]
  __shared__ __align__(16) unsigned short sH[BP][K2P];   // hidden bf16 (wave-private rows)
  __shared__ __align__(16) unsigned short sW2[H2][K2P];  // W2^T bf16 [n][k]
  __shared__ __align__(16) float sB1[H1];
  __shared__ __align__(16) float sB2[H2];

  const int t    = threadIdx.x;
  const int w    = t >> 6;
  const int lane = t & 63;
  const int quad = lane >> 4, l16 = lane & 15;
  const int m0   = w * 16;                 // this wave's 16-row M tile

  // ---------------- one-time staging (conflict-free, chunk-granular) ----------------
  if (t < 32)            *(f32x4*)&sB1[t * 4]        = *(const f32x4*)&b1[t * 4];
  else if (t < 48)       *(f32x4*)&sB2[(t - 32) * 4] = *(const f32x4*)&b2[(t - 32) * 4];

  // W1 [67][128] -> sW1[n][k]: task = (n, kc); 8 stride-128 coalesced loads -> 1 b128 write
  #pragma unroll
  for (int i = 0; i < 6; ++i) {            // 128 n * 12 kc = 1536 tasks
    int task = t + 256 * i;
    int n = task & 127, kc = task >> 7;
    u16x8 h;
    #pragma unroll
    for (int j = 0; j < 8; ++j) {
      int k = kc * 8 + j;
      float v = (k < 67) ? W1[k * H1 + n] : 0.f;
      h[j] = f2b(v);
    }
    *(u16x8*)&sW1[n][kc * 8] = h;
  }
  // W2 [128][64] -> sW2[n][k]
  #pragma unroll
  for (int i = 0; i < 4; ++i) {            // 64 n * 16 kc = 1024 tasks
    int task = t + 256 * i;
    int n = task & 63, kc = task >> 6;
    u16x8 h;
    #pragma unroll
    for (int j = 0; j < 8; ++j) h[j] = f2b(W2[(kc * 8 + j) * H2 + n]);
    *(u16x8*)&sW2[n][kc * 8] = h;
  }
  // zero this wave's sX pad chunks 9..11 (k=72..95) once; chunk 8 rewritten every iter
  if (lane < 48) {
    int r = lane & 15, c = 9 + (lane >> 4);
    u16x8 z = {0, 0, 0, 0, 0, 0, 0, 0};
    *(u16x8*)&sX[m0 + r][c * 8] = z;
  }
  __syncthreads();                         // the ONLY barrier

  // hoist per-lane biases (loop-invariant)
  float bias1[8], bias2[4];
  #pragma unroll
  for (int nt = 0; nt < 8; ++nt) bias1[nt] = sB1[nt * 16 + l16];
  #pragma unroll
  for (int nt = 0; nt < 4; ++nt) bias2[nt] = sB2[nt * 16 + l16];

  // ---------------- main loop: 16 tiles, no barriers (all wave-private) ----------------
  for (int it = 0; it < ITERS; ++it) {
    const int p0 = (blockIdx.x * ITERS + it) * BP;

    // gather: this wave fills sX rows m0..m0+15, chunks 0..7 (k=0..63)
    #pragma unroll
    for (int i = 0; i < 2; ++i) {          // 16 rows * 8 chunks = 128 tasks / 64 lanes
      int task = lane + 64 * i;
      int row = task >> 3, kc = task & 7;
      int lab = labels[p0 + m0 + row];
      if (use_bf) {
        *(u16x8*)&sX[m0 + row][kc * 8] = *(const u16x8*)&featbf[lab * DF + kc * 8];
      } else {
        f32x4 v0 = *(const f32x4*)&feat[lab * DF + kc * 8];
        f32x4 v1 = *(const f32x4*)&feat[lab * DF + kc * 8 + 4];
        u16x8 h;
        #pragma unroll
        for (int j = 0; j < 4; ++j) { h[j] = f2b(v0[j]); h[j + 4] = f2b(v1[j]); }
        *(u16x8*)&sX[m0 + row][kc * 8] = h;
      }
    }
    // chunk 8: coord diffs + zeros (k=64..71)
    if (lane < 16) {
      int row = lane, p = p0 + m0 + row;
      int lab = labels[p];
      u16x8 h = {0, 0, 0, 0, 0, 0, 0, 0};
      #pragma unroll
      for (int j = 0; j < 3; ++j) h[j] = f2b(centers[lab * 3 + j] - points[p * 3 + j]);
      *(u16x8*)&sX[m0 + row][DF] = h;
    }

    // GEMM1: [16,96] x [96,128]
    f32x4 acc[8];
    #pragma unroll
    for (int i = 0; i < 8; ++i) acc[i] = (f32x4){0.f, 0.f, 0.f, 0.f};
    #pragma unroll
    for (int ks = 0; ks < 3; ++ks) {
      int k0 = ks * 32 + quad * 8;
      bf16x8 a = *(const bf16x8*)&sX[m0 + l16][k0];
      #pragma unroll
      for (int nt = 0; nt < 8; ++nt) {
        bf16x8 b = *(const bf16x8*)&sW1[nt * 16 + l16][k0];
        acc[nt] = __builtin_amdgcn_mfma_f32_16x16x32_bf16(a, b, acc[nt], 0, 0, 0);
      }
    }
    // epilogue 1: bias + relu -> bf16 -> sH (wave-private)
    #pragma unroll
    for (int nt = 0; nt < 8; ++nt) {
      int n = nt * 16 + l16;
      #pragma unroll
      for (int r = 0; r < 4; ++r) {
        float v = acc[nt][r] + bias1[nt];
        v = v > 0.f ? v : 0.f;
        sH[m0 + quad * 4 + r][n] = f2b(v);
      }
    }

    // GEMM2: [16,128] x [128,64]
    f32x4 acc2[4];
    #pragma unroll
    for (int i = 0; i < 4; ++i) acc2[i] = (f32x4){0.f, 0.f, 0.f, 0.f};
    #pragma unroll
    for (int ks = 0; ks < 4; ++ks) {
      int k0 = ks * 32 + quad * 8;
      bf16x8 a = *(const bf16x8*)&sH[m0 + l16][k0];
      #pragma unroll
      for (int nt = 0; nt < 4; ++nt) {
        bf16x8 b = *(const bf16x8*)&sW2[nt * 16 + l16][k0];
        acc2[nt] = __builtin_amdgcn_mfma_f32_16x16x32_bf16(a, b, acc2[nt], 0, 0, 0);
      }
    }
    // epilogue 2: bias + relu -> fp32 global
    #pragma unroll
    for (int nt = 0; nt < 4; ++nt) {
      int n = nt * 16 + l16;
      #pragma unroll
      for (int r = 0; r < 4; ++r) {
        float v = acc2[nt][r] + bias2[nt];
        v = v > 0.f ? v : 0.f;
        out[(long)(p0 + m0 + quad * 4 + r) * H2 + n] = v;
      }
    }
  }
}

extern "C" void kernel_launch(void* const* d_in, const int* in_sizes, int n_in,
                              void* d_out, int out_size, void* d_ws, size_t ws_size,
                              hipStream_t stream) {
  const float* feat   = (const float*)d_in[0];
  const int*   labels = (const int*)d_in[1];
  const float* cen    = (const float*)d_in[2];
  const float* pts    = (const float*)d_in[3];
  const float* W1     = (const float*)d_in[4];
  const float* b1     = (const float*)d_in[5];
  const float* W2     = (const float*)d_in[6];
  const float* b2     = (const float*)d_in[7];
  float*       outp   = (float*)d_out;

  const size_t featbf_bytes = (size_t)NCLU * DF * sizeof(unsigned short);  // 2 MB
  int use_bf = (ws_size >= featbf_bytes) ? 1 : 0;
  unsigned short* featbf = (unsigned short*)d_ws;

  if (use_bf)
    cvt_feat<<<dim3(NCLU * DF / (256 * 4)), dim3(256), 0, stream>>>(feat, featbf);

  fused_gather_mlp<<<dim3(NBLK), dim3(256), 0, stream>>>(
      feat, labels, cen, pts, W1, b1, W2, b2, outp, featbf, use_bf);
}